// Round 11
// baseline (277.469 us; speedup 1.0000x reference)
//
#include <hip/hip_runtime.h>

#define L2E 1.4426950408889634f

#define BB   32      // batch
#define HH   4096    // hidden
#define NH   32      // n heads
#define NKV  8       // n kv heads
#define GG   4       // NH/NKV
#define DD   128     // head dim
#define SWIN 4096    // cache window
#define NQK  6144    // 4096 q + 1024 k + 1024 v
#define QSPL 32      // K-split for qkv projection (4096/128)
#define DSPL 16      // K-split for dense projection (4096/256)
#define ASPL 4       // sequence splits for attention

typedef float f4 __attribute__((ext_vector_type(4)));

__device__ __forceinline__ float xsh(float v, int off) {
    return __shfl_xor(v, off, 64);
}

__device__ __forceinline__ f4 ntload(const float* p) {
    return __builtin_nontemporal_load(reinterpret_cast<const f4*>(p));
}

// ---------------- Unified skinny projection GEMM (templated K-chunk) ----------
// C[32 x npart] = X[32 x 4096] @ W, K-split partials.
// grid (nstripes, 4096/KCH), block 256 = 4 waves. Block: (stripe: 256 cols,
// kb: KCH K-rows). Wave w owns K-rows [w*KCH/4, +KCH/4): every W element
// loaded ONCE, 1KB contiguous dwordx4 per wave-instr. X staged in LDS
// transposed+swizzled. No launch_bounds cap beyond 256: acc[32] f4 needs
// ~220 VGPR — capping to 128 spills and costs 2x (R9 post-mortem).
template<int KCH>
__global__ __launch_bounds__(256) void gemm_skinny(const float* __restrict__ X,
                                                   const float* __restrict__ w0,
                                                   const float* __restrict__ w1,
                                                   const float* __restrict__ w2,
                                                   int s1, int s2,
                                                   float* __restrict__ part,
                                                   int npart) {
    const int stripe = blockIdx.x;
    const int kb = blockIdx.y;
    const int t = threadIdx.x;
    const int w = t >> 6;
    const int lane = t & 63;
    const int k0 = kb * KCH;
    constexpr int RPW = KCH / 4;    // rows per wave

    const float* W;
    int stride, cb;
    if (stripe < s1)      { W = w0; stride = 4096; cb = stripe * 256; }
    else if (stripe < s2) { W = w1; stride = 1024; cb = (stripe - s1) * 256; }
    else                  { W = w2; stride = 1024; cb = (stripe - s2) * 256; }

    const float* wp = W + (size_t)(k0 + w * RPW) * stride + cb + lane * 4;

    // prologue: first W group in flight before staging barrier
    f4 wn[4];
#pragma unroll
    for (int rr = 0; rr < 4; ++rr)
        wn[rr] = ntload(wp + (size_t)rr * stride);

    // stage xT[k][b] swizzled: lds[k*32 + (b ^ (((k>>2)&7)<<2))]
    __shared__ float lds[8192];
    for (int i = t; i < 8 * KCH; i += 256) {
        const int b = i / (KCH / 4);
        const int k4 = (i % (KCH / 4)) * 4;
        const f4 v = *reinterpret_cast<const f4*>(X + (size_t)b * HH + k0 + k4);
        const int colb = b ^ (((k4 >> 2) & 7) << 2);
        lds[(k4 + 0) * 32 + colb] = v.x;
        lds[(k4 + 1) * 32 + colb] = v.y;
        lds[(k4 + 2) * 32 + colb] = v.z;
        lds[(k4 + 3) * 32 + colb] = v.w;
    }
    __syncthreads();

    f4 acc[32];
#pragma unroll
    for (int b = 0; b < 32; ++b) acc[b] = (f4){0.f, 0.f, 0.f, 0.f};

    for (int g = 0; g < KCH / 16; ++g) {
        f4 wcur[4];
#pragma unroll
        for (int rr = 0; rr < 4; ++rr) wcur[rr] = wn[rr];
        if (g < KCH / 16 - 1) {
#pragma unroll
            for (int rr = 0; rr < 4; ++rr)
                wn[rr] = ntload(wp + (size_t)((g + 1) * 4 + rr) * stride);
        }
#pragma unroll
        for (int rr = 0; rr < 4; ++rr) {
            const int r = w * RPW + g * 4 + rr;
            const int swr = ((r >> 2) & 7) << 2;
            const float* xrow = lds + r * 32;
            f4 xb[8];
#pragma unroll
            for (int j = 0; j < 8; ++j)
                xb[j] = *reinterpret_cast<const f4*>(xrow + ((4 * j) ^ swr));
#pragma unroll
            for (int b = 0; b < 32; ++b) {
                const float xs = xb[b >> 2][b & 3];
                acc[b] += wcur[rr] * xs;
            }
        }
    }

    // cross-wave reduce: 4 rounds of 8 batches, lds reused (8192 floats)
#pragma unroll
    for (int bg = 0; bg < 4; ++bg) {
        __syncthreads();
#pragma unroll
        for (int i = 0; i < 8; ++i)
            *reinterpret_cast<f4*>(&lds[(w * 8 + i) * 256 + lane * 4]) = acc[bg * 8 + i];
        __syncthreads();
#pragma unroll
        for (int i = 0; i < 8; ++i) {
            const float v = lds[(0 * 8 + i) * 256 + t] + lds[(1 * 8 + i) * 256 + t] +
                            lds[(2 * 8 + i) * 256 + t] + lds[(3 * 8 + i) * 256 + t];
            part[((size_t)kb * BB + bg * 8 + i) * npart + stripe * 256 + t] = v;
        }
    }
}

// ---------------- Kernel 2: reduce K-split partials + rotate q/k, scatter v ----
__global__ __launch_bounds__(128) void rot_kernel(const float* __restrict__ part,
                                                  const float* __restrict__ rot,
                                                  float* __restrict__ q_rot,
                                                  float* __restrict__ k_new,
                                                  float* __restrict__ v_new) {
    const int blk = blockIdx.x;
    const int e = threadIdx.x;  // 0..127

    int kind, b, head;
    if (blk < 1024)      { kind = 0; b = blk >> 5;          head = blk & 31; }
    else if (blk < 1280) { kind = 1; b = (blk - 1024) >> 3; head = (blk - 1024) & 7; }
    else                 { kind = 2; b = (blk - 1280) >> 3; head = (blk - 1280) & 7; }

    const int ncol = (kind == 0) ? head * DD
                   : (kind == 1) ? 4096 + head * DD
                                 : 5120 + head * DD;

    float val = 0.f;
#pragma unroll 8
    for (int s = 0; s < QSPL; ++s)
        val += part[((size_t)s * BB + b) * NQK + ncol + e];

    if (kind == 2) {
        v_new[(size_t)(head * BB + b) * DD + e] = val;
        return;
    }

    __shared__ float row[DD];
    row[e] = val;
    __syncthreads();

    float acc = 0.f;
#pragma unroll 4
    for (int d = 0; d < DD; ++d)
        acc = fmaf(row[d], rot[d * DD + e], acc);

    if (kind == 0) {
        acc *= 0.08838834764831845f;  // D^-0.5
        const int hk = head >> 2, g = head & 3;
        q_rot[((size_t)(hk * BB + b) * GG + g) * DD + e] = acc;
    } else {
        k_new[(size_t)(head * BB + b) * DD + e] = acc;
    }
}

// ---------------- attention main loop (templated: HASCUR waves keep the
// current_pos pointer-select; the 63/64 other waves run select-free) ----------
template<bool HASCUR>
__device__ __forceinline__ void attn_loop(const float* __restrict__ kc,
                                          const float* __restrict__ vc,
                                          const float* __restrict__ kn,
                                          const float* __restrict__ vn,
                                          int current_pos, int p_begin, int p_end,
                                          int lsm1, int sub, int off0,
                                          const f4 qa[GG], float M[GG],
                                          float L[GG], f4 oa[GG]) {
    auto rowk = [&](int p) {
        const float* base = kc + (size_t)p * DD;
        if (HASCUR) { if (p == current_pos) base = kn; }
        return base + off0;
    };
    auto rowv = [&](int p) {
        const float* base = vc + (size_t)p * DD;
        if (HASCUR) { if (p == current_pos) base = vn; }
        return base + off0;
    };

    const int pc0 = min(p_begin + sub, lsm1);
    f4 ck = ntload(rowk(pc0));
    f4 cv = ntload(rowv(pc0));

    for (int p0 = p_begin; p0 < p_end; p0 += 2) {
        const int pn = min(p0 + 2 + sub, lsm1);
        const f4 nk = ntload(rowk(pn));
        const f4 nv = ntload(rowv(pn));

        const bool valid = (p0 + sub) < p_end;

        float s[GG];
#pragma unroll
        for (int g = 0; g < GG; ++g) {
            float a = 0.f;
            a = fmaf(qa[g].x, ck.x, a);
            a = fmaf(qa[g].y, ck.y, a);
            a = fmaf(qa[g].z, ck.z, a);
            a = fmaf(qa[g].w, ck.w, a);
            s[g] = a;
        }
#pragma unroll
        for (int off = 1; off <= 16; off <<= 1) {
#pragma unroll
            for (int g = 0; g < GG; ++g) s[g] += xsh(s[g], off);
        }
        if (!valid) {
#pragma unroll
            for (int g = 0; g < GG; ++g) s[g] = -INFINITY;
        }
#pragma unroll
        for (int g = 0; g < GG; ++g) {
            const float nM = fmaxf(M[g], s[g]);
            const float e0 = exp2f((M[g] - nM) * L2E);
            const float pe = exp2f((s[g] - nM) * L2E);
            M[g] = nM;
            L[g] = fmaf(L[g], e0, pe);
            oa[g].x = fmaf(oa[g].x, e0, pe * cv.x);
            oa[g].y = fmaf(oa[g].y, e0, pe * cv.y);
            oa[g].z = fmaf(oa[g].z, e0, pe * cv.z);
            oa[g].w = fmaf(oa[g].w, e0, pe * cv.w);
        }

        ck = nk; cv = nv;
    }
}

// ---------------- Kernel 3: flash-decode attention ----------------
// grid (256 pairs, ASPL), block 256 (4 waves) -> 16 streams/pair.
__global__ __launch_bounds__(256) void attn_kernel(const float* __restrict__ q_rot,
                                                   const float* __restrict__ k_new,
                                                   const float* __restrict__ v_new,
                                                   const float* __restrict__ cache_k,
                                                   const float* __restrict__ cache_v,
                                                   const int* __restrict__ spp,
                                                   const int* __restrict__ cpp,
                                                   float* __restrict__ m_part,
                                                   float* __restrict__ l_part,
                                                   float* __restrict__ o_part) {
    const int pair  = blockIdx.x;       // hkv*32 + b
    const int split = blockIdx.y;
    const int start_pos   = *spp;
    const int current_pos = *cpp;
    const int layer_slice = min(start_pos + 1, SWIN);
    const int lsm1 = layer_slice - 1;

    const int tid  = threadIdx.x;
    const int w    = tid >> 6;
    const int lane = tid & 63;
    const int sub  = lane >> 5;   // position sub-slot 0..1
    const int li   = lane & 31;   // dim quad owner
    const int off0 = li * 4;

    const float* qb = q_rot + (size_t)pair * (GG * DD) + off0;
    f4 qa[GG];
#pragma unroll
    for (int g = 0; g < GG; ++g)
        qa[g] = *reinterpret_cast<const f4*>(qb + g * DD);

    const int nstreams = ASPL * 4;
    const int chunk = (layer_slice + nstreams - 1) / nstreams;
    const int wsid = split * 4 + w;
    const int p_begin = wsid * chunk;
    const int p_end = min(p_begin + chunk, layer_slice);

    const float* kc = cache_k + (size_t)pair * SWIN * DD;
    const float* vc = cache_v + (size_t)pair * SWIN * DD;
    const float* kn = k_new + (size_t)pair * DD;
    const float* vn = v_new + (size_t)pair * DD;

    float M[GG] = {-1e30f, -1e30f, -1e30f, -1e30f};
    float L[GG] = {0.f, 0.f, 0.f, 0.f};
    f4 oa[GG];
#pragma unroll
    for (int g = 0; g < GG; ++g) oa[g] = (f4){0.f, 0.f, 0.f, 0.f};

    const bool hascur = (current_pos >= p_begin) && (current_pos < p_end);
    if (hascur)
        attn_loop<true>(kc, vc, kn, vn, current_pos, p_begin, p_end, lsm1,
                        sub, off0, qa, M, L, oa);
    else
        attn_loop<false>(kc, vc, kn, vn, current_pos, p_begin, p_end, lsm1,
                         sub, off0, qa, M, L, oa);

    // merge 2 position sub-groups (xor bit 5)
    {
        const int off = 32;
#pragma unroll
        for (int g = 0; g < GG; ++g) {
            const float Mo = xsh(M[g], off);
            const float Lo = xsh(L[g], off);
            const float nM = fmaxf(M[g], Mo);
            const float e0 = exp2f((M[g] - nM) * L2E);
            const float e1 = exp2f((Mo - nM) * L2E);
            M[g] = nM;
            L[g] = L[g] * e0 + Lo * e1;
            oa[g].x = oa[g].x * e0 + xsh(oa[g].x, off) * e1;
            oa[g].y = oa[g].y * e0 + xsh(oa[g].y, off) * e1;
            oa[g].z = oa[g].z * e0 + xsh(oa[g].z, off) * e1;
            oa[g].w = oa[g].w * e0 + xsh(oa[g].w, off) * e1;
        }
    }

    // merge the 4 waves via LDS -> split partials
    __shared__ float sM[4][GG], sL[4][GG];
    __shared__ float sO[4][GG][DD];
    if (sub == 0) {
#pragma unroll
        for (int g = 0; g < GG; ++g) {
            sO[w][g][off0 + 0] = oa[g].x;
            sO[w][g][off0 + 1] = oa[g].y;
            sO[w][g][off0 + 2] = oa[g].z;
            sO[w][g][off0 + 3] = oa[g].w;
            if (li == 0) { sM[w][g] = M[g]; sL[w][g] = L[g]; }
        }
    }
    __syncthreads();

    for (int item = tid; item < GG * DD; item += 256) {
        const int g = item >> 7;
        const int d = item & 127;
        const float m0 = sM[0][g], m1 = sM[1][g], m2 = sM[2][g], m3 = sM[3][g];
        const float nM = fmaxf(fmaxf(m0, m1), fmaxf(m2, m3));
        const float e0 = exp2f((m0 - nM) * L2E);
        const float e1 = exp2f((m1 - nM) * L2E);
        const float e2 = exp2f((m2 - nM) * L2E);
        const float e3 = exp2f((m3 - nM) * L2E);
        const float lt = sL[0][g] * e0 + sL[1][g] * e1 + sL[2][g] * e2 + sL[3][g] * e3;
        const float od = sO[0][g][d] * e0 + sO[1][g][d] * e1 +
                         sO[2][g][d] * e2 + sO[3][g][d] * e3;
        const size_t base = ((size_t)pair * GG + g) * ASPL + split;
        if (d == 0) { m_part[base] = nM; l_part[base] = lt; }
        o_part[base * DD + d] = od;
    }
}

// ---------------- Kernel 4: merge splits -> attn_out[b][n] ----------------
__global__ __launch_bounds__(256) void attn_reduce(const float* __restrict__ m_part,
                                                   const float* __restrict__ l_part,
                                                   const float* __restrict__ o_part,
                                                   float* __restrict__ attn_out) {
    const int idx = blockIdx.x * 256 + threadIdx.x;  // < 256*4*128
    const int d = idx & 127;
    const int pg = idx >> 7;

    float nM = -1e30f;
#pragma unroll
    for (int s = 0; s < ASPL; ++s) nM = fmaxf(nM, m_part[pg * ASPL + s]);

    float lt = 0.f, od = 0.f;
#pragma unroll
    for (int s = 0; s < ASPL; ++s) {
        const float e = exp2f((m_part[pg * ASPL + s] - nM) * L2E);
        lt = fmaf(l_part[pg * ASPL + s], e, lt);
        od = fmaf(o_part[(size_t)(pg * ASPL + s) * DD + d], e, od);
    }

    const int pair = pg >> 2, g = pg & 3;
    const int h = pair >> 5, b = pair & 31;
    attn_out[(size_t)b * HH + (h * GG + g) * DD + d] = od / fmaxf(lt, 1e-30f);
}

// ---------------- Kernel 6: reduce dense partials -> d_out ----------------
__global__ __launch_bounds__(256) void reduce_dense(const float* __restrict__ part,
                                                    float* __restrict__ out) {
    const int idx = blockIdx.x * 256 + threadIdx.x;  // < 32*4096
    float a = 0.f;
#pragma unroll
    for (int s = 0; s < DSPL; ++s) a += part[(size_t)s * (BB * HH) + idx];
    out[idx] = a;
}

extern "C" void kernel_launch(void* const* d_in, const int* in_sizes, int n_in,
                              void* d_out, int out_size, void* d_ws, size_t ws_size,
                              hipStream_t stream) {
    const float* x       = (const float*)d_in[0];
    const float* wq      = (const float*)d_in[1];
    const float* wk      = (const float*)d_in[2];
    const float* wv      = (const float*)d_in[3];
    const float* wo      = (const float*)d_in[4];
    const float* rotm    = (const float*)d_in[5];
    const float* cache_k = (const float*)d_in[6];
    const float* cache_v = (const float*)d_in[7];
    const int*   spp     = (const int*)d_in[8];
    const int*   cpp     = (const int*)d_in[9];
    float* out = (float*)d_out;
    float* ws  = (float*)d_ws;

    // workspace layout (floats)
    float* part_qkv = ws;                       // 32*32*6144  = 6,291,456
    float* q_rot    = part_qkv + 6291456;       // 131,072
    float* k_new    = q_rot + 131072;           // 32,768
    float* v_new    = k_new + 32768;            // 32,768
    float* m_part   = v_new + 32768;            // 4,096 (pad to 8,192)
    float* l_part   = m_part + 8192;            // 4,096 (pad to 8,192)
    float* o_part   = l_part + 8192;            // 524,288 (pad to 1,048,576)
    float* attn_out = o_part + 1048576;         // 131,072
    float* part_d   = attn_out + 131072;        // 16*32*4096 = 2,097,152

    // qkv: KCH=128 x 32 splits -> grid 768 = 3 blocks/CU exactly (balanced)
    gemm_skinny<128><<<dim3(24, QSPL), 256, 0, stream>>>(x, wq, wk, wv, 16, 20,
                                                         part_qkv, NQK);
    rot_kernel<<<1536, 128, 0, stream>>>(part_qkv, rotm, q_rot, k_new, v_new);
    attn_kernel<<<dim3(256, ASPL), 256, 0, stream>>>(q_rot, k_new, v_new,
                                                     cache_k, cache_v, spp, cpp,
                                                     m_part, l_part, o_part);
    attn_reduce<<<512, 256, 0, stream>>>(m_part, l_part, o_part, attn_out);
    // dense: KCH=256 x 16 splits -> grid 256 = 1 block/CU exactly
    gemm_skinny<256><<<dim3(16, DSPL), 256, 0, stream>>>(attn_out, wo, wo, wo, 16, 20,
                                                         part_d, HH);
    reduce_dense<<<512, 256, 0, stream>>>(part_d, out);
}

// Round 12
// 270.094 us; speedup vs baseline: 1.0273x; 1.0273x over previous
//
#include <hip/hip_runtime.h>

#define L2E 1.4426950408889634f

#define BB   32      // batch
#define HH   4096    // hidden
#define NH   32      // n heads
#define NKV  8       // n kv heads
#define GG   4       // NH/NKV
#define DD   128     // head dim
#define SWIN 4096    // cache window
#define NQK  6144    // 4096 q + 1024 k + 1024 v
#define KSPL 16      // K-split for projections (4096/256)
#define ASPL 8       // sequence splits for attention

typedef float f4 __attribute__((ext_vector_type(4)));

__device__ __forceinline__ float xsh(float v, int off) {
    return __shfl_xor(v, off, 64);
}

__device__ __forceinline__ f4 ntload(const float* p) {
    return __builtin_nontemporal_load(reinterpret_cast<const f4*>(p));
}

// ---------------- Unified skinny projection GEMM (R5/R10-proven, 32 KB LDS) -----
// C[32 x npart] = X[32 x 4096] @ W, K-split partials.
// grid (nstripes, 16), block 256 = 4 waves. Block: (stripe: 256 cols,
// kb: 256 K-rows). Wave w owns K-rows [w*64, +64): every W element loaded ONCE,
// 1KB contiguous dwordx4 per wave-instr. X staged in LDS transposed+swizzled.
// NO launch_bounds cap beyond 256 threads: acc[32] f4 needs ~220 VGPR — capping
// to 128 spills the accumulator and costs 2x (R9 post-mortem).
__global__ __launch_bounds__(256) void gemm_skinny(const float* __restrict__ X,
                                                   const float* __restrict__ w0,
                                                   const float* __restrict__ w1,
                                                   const float* __restrict__ w2,
                                                   int s1, int s2,
                                                   float* __restrict__ part,
                                                   int npart) {
    const int stripe = blockIdx.x;
    const int kb = blockIdx.y;
    const int t = threadIdx.x;
    const int w = t >> 6;
    const int lane = t & 63;
    const int k0 = kb * 256;

    const float* W;
    int stride, cb;
    if (stripe < s1)      { W = w0; stride = 4096; cb = stripe * 256; }
    else if (stripe < s2) { W = w1; stride = 1024; cb = (stripe - s1) * 256; }
    else                  { W = w2; stride = 1024; cb = (stripe - s2) * 256; }

    const float* wp = W + (size_t)(k0 + w * 64) * stride + cb + lane * 4;

    // prologue: first W group in flight before staging barrier
    f4 wn[4];
#pragma unroll
    for (int rr = 0; rr < 4; ++rr)
        wn[rr] = ntload(wp + (size_t)rr * stride);

    // stage xT[k][b] swizzled: lds[k*32 + (b ^ (((k>>2)&7)<<2))]
    __shared__ float lds[8192];
    for (int i = t; i < 2048; i += 256) {
        const int b = i >> 6;
        const int k4 = (i & 63) * 4;
        const f4 v = *reinterpret_cast<const f4*>(X + (size_t)b * HH + k0 + k4);
        const int colb = b ^ (((k4 >> 2) & 7) << 2);
        lds[(k4 + 0) * 32 + colb] = v.x;
        lds[(k4 + 1) * 32 + colb] = v.y;
        lds[(k4 + 2) * 32 + colb] = v.z;
        lds[(k4 + 3) * 32 + colb] = v.w;
    }
    __syncthreads();

    f4 acc[32];
#pragma unroll
    for (int b = 0; b < 32; ++b) acc[b] = (f4){0.f, 0.f, 0.f, 0.f};

    for (int g = 0; g < 16; ++g) {
        f4 wcur[4];
#pragma unroll
        for (int rr = 0; rr < 4; ++rr) wcur[rr] = wn[rr];
        if (g < 15) {
#pragma unroll
            for (int rr = 0; rr < 4; ++rr)
                wn[rr] = ntload(wp + (size_t)((g + 1) * 4 + rr) * stride);
        }
#pragma unroll
        for (int rr = 0; rr < 4; ++rr) {
            const int r = w * 64 + g * 4 + rr;
            const int swr = ((r >> 2) & 7) << 2;
            const float* xrow = lds + r * 32;
            f4 xb[8];
#pragma unroll
            for (int j = 0; j < 8; ++j)
                xb[j] = *reinterpret_cast<const f4*>(xrow + ((4 * j) ^ swr));
#pragma unroll
            for (int b = 0; b < 32; ++b) {
                const float xs = xb[b >> 2][b & 3];
                acc[b] += wcur[rr] * xs;
            }
        }
    }

    // cross-wave reduce: 4 rounds of 8 batches, lds reused (8192 floats)
#pragma unroll
    for (int bg = 0; bg < 4; ++bg) {
        __syncthreads();
#pragma unroll
        for (int i = 0; i < 8; ++i)
            *reinterpret_cast<f4*>(&lds[(w * 8 + i) * 256 + lane * 4]) = acc[bg * 8 + i];
        __syncthreads();
#pragma unroll
        for (int i = 0; i < 8; ++i) {
            const float v = lds[(0 * 8 + i) * 256 + t] + lds[(1 * 8 + i) * 256 + t] +
                            lds[(2 * 8 + i) * 256 + t] + lds[(3 * 8 + i) * 256 + t];
            part[((size_t)kb * BB + bg * 8 + i) * npart + stripe * 256 + t] = v;
        }
    }
}

// ---------------- Kernel 2: reduce K-split partials + rotate q/k, scatter v ----
__global__ __launch_bounds__(128) void rot_kernel(const float* __restrict__ part,
                                                  const float* __restrict__ rot,
                                                  float* __restrict__ q_rot,
                                                  float* __restrict__ k_new,
                                                  float* __restrict__ v_new) {
    const int blk = blockIdx.x;
    const int e = threadIdx.x;  // 0..127

    int kind, b, head;
    if (blk < 1024)      { kind = 0; b = blk >> 5;          head = blk & 31; }
    else if (blk < 1280) { kind = 1; b = (blk - 1024) >> 3; head = (blk - 1024) & 7; }
    else                 { kind = 2; b = (blk - 1280) >> 3; head = (blk - 1280) & 7; }

    const int ncol = (kind == 0) ? head * DD
                   : (kind == 1) ? 4096 + head * DD
                                 : 5120 + head * DD;

    float val = 0.f;
#pragma unroll
    for (int s = 0; s < KSPL; ++s)
        val += part[((size_t)s * BB + b) * NQK + ncol + e];

    if (kind == 2) {
        v_new[(size_t)(head * BB + b) * DD + e] = val;
        return;
    }

    __shared__ float row[DD];
    row[e] = val;
    __syncthreads();

    float acc = 0.f;
#pragma unroll 4
    for (int d = 0; d < DD; ++d)
        acc = fmaf(row[d], rot[d * DD + e], acc);

    if (kind == 0) {
        acc *= 0.08838834764831845f;  // D^-0.5
        const int hk = head >> 2, g = head & 3;
        q_rot[((size_t)(hk * BB + b) * GG + g) * DD + e] = acc;
    } else {
        k_new[(size_t)(head * BB + b) * DD + e] = acc;
    }
}

// ---------------- Kernel 3: flash-decode attention (184 us, ~92% of HBM ceiling) -
__global__ __launch_bounds__(256) void attn_kernel(const float* __restrict__ q_rot,
                                                   const float* __restrict__ k_new,
                                                   const float* __restrict__ v_new,
                                                   const float* __restrict__ cache_k,
                                                   const float* __restrict__ cache_v,
                                                   const int* __restrict__ spp,
                                                   const int* __restrict__ cpp,
                                                   float* __restrict__ m_part,
                                                   float* __restrict__ l_part,
                                                   float* __restrict__ o_part) {
    const int pair  = blockIdx.x;       // hkv*32 + b
    const int split = blockIdx.y;
    const int start_pos   = *spp;
    const int current_pos = *cpp;
    const int layer_slice = min(start_pos + 1, SWIN);

    const int tid  = threadIdx.x;
    const int w    = tid >> 6;
    const int lane = tid & 63;
    const int sub  = lane >> 5;   // position sub-slot 0..1
    const int li   = lane & 31;   // dim quad owner

    const float* qb = q_rot + (size_t)pair * (GG * DD) + li * 4;
    f4 qa[GG];
#pragma unroll
    for (int g = 0; g < GG; ++g)
        qa[g] = *reinterpret_cast<const f4*>(qb + g * DD);

    const int nstreams = ASPL * 4;
    const int chunk = (layer_slice + nstreams - 1) / nstreams;
    const int wsid = split * 4 + w;
    const int p_begin = wsid * chunk;
    const int p_end = min(p_begin + chunk, layer_slice);

    const float* kc = cache_k + (size_t)pair * SWIN * DD;
    const float* vc = cache_v + (size_t)pair * SWIN * DD;
    const float* kn = k_new + (size_t)pair * DD;
    const float* vn = v_new + (size_t)pair * DD;

    float M[GG] = {-1e30f, -1e30f, -1e30f, -1e30f};
    float L[GG] = {0.f, 0.f, 0.f, 0.f};
    f4 oa[GG];
#pragma unroll
    for (int g = 0; g < GG; ++g) oa[g] = (f4){0.f, 0.f, 0.f, 0.f};

    const int off0 = li * 4;
    auto rowk = [&](int p) {
        return ((p == current_pos) ? kn : kc + (size_t)p * DD) + off0;
    };
    auto rowv = [&](int p) {
        return ((p == current_pos) ? vn : vc + (size_t)p * DD) + off0;
    };

    const int pc0 = min(p_begin + sub, layer_slice - 1);
    f4 ck = ntload(rowk(pc0));
    f4 cv = ntload(rowv(pc0));

    for (int p0 = p_begin; p0 < p_end; p0 += 2) {
        const int pn = min(p0 + 2 + sub, layer_slice - 1);
        const f4 nk = ntload(rowk(pn));
        const f4 nv = ntload(rowv(pn));

        const bool valid = (p0 + sub) < p_end;

        float s[GG];
#pragma unroll
        for (int g = 0; g < GG; ++g) {
            float a = 0.f;
            a = fmaf(qa[g].x, ck.x, a);
            a = fmaf(qa[g].y, ck.y, a);
            a = fmaf(qa[g].z, ck.z, a);
            a = fmaf(qa[g].w, ck.w, a);
            s[g] = a;
        }
#pragma unroll
        for (int off = 1; off <= 16; off <<= 1) {
#pragma unroll
            for (int g = 0; g < GG; ++g) s[g] += xsh(s[g], off);
        }
        if (!valid) {
#pragma unroll
            for (int g = 0; g < GG; ++g) s[g] = -INFINITY;
        }
#pragma unroll
        for (int g = 0; g < GG; ++g) {
            const float nM = fmaxf(M[g], s[g]);
            const float e0 = exp2f((M[g] - nM) * L2E);
            const float pe = exp2f((s[g] - nM) * L2E);
            M[g] = nM;
            L[g] = fmaf(L[g], e0, pe);
            oa[g].x = fmaf(oa[g].x, e0, pe * cv.x);
            oa[g].y = fmaf(oa[g].y, e0, pe * cv.y);
            oa[g].z = fmaf(oa[g].z, e0, pe * cv.z);
            oa[g].w = fmaf(oa[g].w, e0, pe * cv.w);
        }

        ck = nk; cv = nv;
    }

    {
        const int off = 32;
#pragma unroll
        for (int g = 0; g < GG; ++g) {
            const float Mo = xsh(M[g], off);
            const float Lo = xsh(L[g], off);
            const float nM = fmaxf(M[g], Mo);
            const float e0 = exp2f((M[g] - nM) * L2E);
            const float e1 = exp2f((Mo - nM) * L2E);
            M[g] = nM;
            L[g] = L[g] * e0 + Lo * e1;
            oa[g].x = oa[g].x * e0 + xsh(oa[g].x, off) * e1;
            oa[g].y = oa[g].y * e0 + xsh(oa[g].y, off) * e1;
            oa[g].z = oa[g].z * e0 + xsh(oa[g].z, off) * e1;
            oa[g].w = oa[g].w * e0 + xsh(oa[g].w, off) * e1;
        }
    }

    __shared__ float sM[4][GG], sL[4][GG];
    __shared__ float sO[4][GG][DD];
    if (sub == 0) {
#pragma unroll
        for (int g = 0; g < GG; ++g) {
            sO[w][g][off0 + 0] = oa[g].x;
            sO[w][g][off0 + 1] = oa[g].y;
            sO[w][g][off0 + 2] = oa[g].z;
            sO[w][g][off0 + 3] = oa[g].w;
            if (li == 0) { sM[w][g] = M[g]; sL[w][g] = L[g]; }
        }
    }
    __syncthreads();

    for (int item = tid; item < GG * DD; item += 256) {
        const int g = item >> 7;
        const int d = item & 127;
        const float m0 = sM[0][g], m1 = sM[1][g], m2 = sM[2][g], m3 = sM[3][g];
        const float nM = fmaxf(fmaxf(m0, m1), fmaxf(m2, m3));
        const float e0 = exp2f((m0 - nM) * L2E);
        const float e1 = exp2f((m1 - nM) * L2E);
        const float e2 = exp2f((m2 - nM) * L2E);
        const float e3 = exp2f((m3 - nM) * L2E);
        const float lt = sL[0][g] * e0 + sL[1][g] * e1 + sL[2][g] * e2 + sL[3][g] * e3;
        const float od = sO[0][g][d] * e0 + sO[1][g][d] * e1 +
                         sO[2][g][d] * e2 + sO[3][g][d] * e3;
        const size_t base = ((size_t)pair * GG + g) * ASPL + split;
        if (d == 0) { m_part[base] = nM; l_part[base] = lt; }
        o_part[base * DD + d] = od;
    }
}

// ---------------- Kernel 4: merge splits -> attn_out[b][n] ----------------
__global__ __launch_bounds__(256) void attn_reduce(const float* __restrict__ m_part,
                                                   const float* __restrict__ l_part,
                                                   const float* __restrict__ o_part,
                                                   float* __restrict__ attn_out) {
    const int idx = blockIdx.x * 256 + threadIdx.x;  // < 256*4*128
    const int d = idx & 127;
    const int pg = idx >> 7;

    float nM = -1e30f;
#pragma unroll
    for (int s = 0; s < ASPL; ++s) nM = fmaxf(nM, m_part[pg * ASPL + s]);

    float lt = 0.f, od = 0.f;
#pragma unroll
    for (int s = 0; s < ASPL; ++s) {
        const float e = exp2f((m_part[pg * ASPL + s] - nM) * L2E);
        lt = fmaf(l_part[pg * ASPL + s], e, lt);
        od = fmaf(o_part[(size_t)(pg * ASPL + s) * DD + d], e, od);
    }

    const int pair = pg >> 2, g = pg & 3;
    const int h = pair >> 5, b = pair & 31;
    attn_out[(size_t)b * HH + (h * GG + g) * DD + d] = od / fmaxf(lt, 1e-30f);
}

// ---------------- Kernel 6: reduce dense partials -> d_out ----------------
__global__ __launch_bounds__(256) void reduce_dense(const float* __restrict__ part,
                                                    float* __restrict__ out) {
    const int idx = blockIdx.x * 256 + threadIdx.x;  // < 32*4096
    float a = 0.f;
#pragma unroll
    for (int s = 0; s < KSPL; ++s) a += part[(size_t)s * (BB * HH) + idx];
    out[idx] = a;
}

extern "C" void kernel_launch(void* const* d_in, const int* in_sizes, int n_in,
                              void* d_out, int out_size, void* d_ws, size_t ws_size,
                              hipStream_t stream) {
    const float* x       = (const float*)d_in[0];
    const float* wq      = (const float*)d_in[1];
    const float* wk      = (const float*)d_in[2];
    const float* wv      = (const float*)d_in[3];
    const float* wo      = (const float*)d_in[4];
    const float* rotm    = (const float*)d_in[5];
    const float* cache_k = (const float*)d_in[6];
    const float* cache_v = (const float*)d_in[7];
    const int*   spp     = (const int*)d_in[8];
    const int*   cpp     = (const int*)d_in[9];
    float* out = (float*)d_out;
    float* ws  = (float*)d_ws;

    // workspace layout (floats)
    float* part_qkv = ws;                       // 16*32*6144  = 3,145,728
    float* q_rot    = part_qkv + 3145728;       // 8*32*4*128  =   131,072
    float* k_new    = q_rot + 131072;           // 8*32*128    =    32,768
    float* v_new    = k_new + 32768;            //             =    32,768
    float* m_part   = v_new + 32768;            // 256*4*8     =     8,192
    float* l_part   = m_part + 8192;            //             =     8,192
    float* o_part   = l_part + 8192;            // 256*4*8*128 = 1,048,576
    float* attn_out = o_part + 1048576;         // 32*4096     =   131,072
    float* part_d   = attn_out + 131072;        // 16*32*4096  = 2,097,152

    // Clean 6-launch chain — best measured configuration (R10: 272.0 us)
    gemm_skinny<<<dim3(24, KSPL), 256, 0, stream>>>(x, wq, wk, wv, 16, 20,
                                                    part_qkv, NQK);
    rot_kernel<<<1536, 128, 0, stream>>>(part_qkv, rotm, q_rot, k_new, v_new);
    attn_kernel<<<dim3(256, ASPL), 256, 0, stream>>>(q_rot, k_new, v_new,
                                                     cache_k, cache_v, spp, cpp,
                                                     m_part, l_part, o_part);
    attn_reduce<<<512, 256, 0, stream>>>(m_part, l_part, o_part, attn_out);
    gemm_skinny<<<dim3(16, KSPL), 256, 0, stream>>>(attn_out, wo, wo, wo, 16, 20,
                                                    part_d, HH);
    reduce_dense<<<512, 256, 0, stream>>>(part_d, out);
}